// Round 4
// baseline (347.922 us; speedup 1.0000x reference)
//
#include <hip/hip_runtime.h>

using bf16 = __bf16;
typedef bf16 bf16x4 __attribute__((ext_vector_type(4)));
typedef bf16 bf16x8 __attribute__((ext_vector_type(8)));
typedef float f32x4 __attribute__((ext_vector_type(4)));
typedef float f32x8 __attribute__((ext_vector_type(8)));

#define MFMA16(a, b, c) __builtin_amdgcn_mfma_f32_16x16x32_bf16(a, b, c, 0, 0, 0)

constexpr int Bb = 4, Tt = 2048, Dd = 1024, Hh = 16, Hd = 64;
constexpr int Mrows = Bb * Tt;                 // 8192
constexpr float CEXP = 0.18033688011112042f;   // (1/sqrt(64)) * log2(e), folded into Wq/bq

// ---------------------------------------------------------------- cast x -> bf16
__global__ void cast_f32_bf16_kernel(const float* __restrict__ in, bf16* __restrict__ out) {
  size_t i = ((size_t)blockIdx.x * 256 + threadIdx.x) * 8;
  f32x8 v = *(const f32x8*)(in + i);
  *(bf16x8*)(out + i) = __builtin_convertvector(v, bf16x8);
}

// ------------------- transpose+cast W[k][n] f32 -> Wt[n][k] bf16, optional scale
__global__ void transpose_cast_w_kernel(const float* __restrict__ W, bf16* __restrict__ Wt,
                                        float scale) {
  __shared__ alignas(16) float tile[64][68];
  const int tid = threadIdx.x;
  const int n0 = blockIdx.x * 64, k0 = blockIdx.y * 64;
#pragma unroll
  for (int it = 0; it < 4; ++it) {
    int chunk = tid + it * 256;        // 1024 chunks: 64 k-rows x 16 float4
    int kr = chunk >> 4, c4 = chunk & 15;
    f32x4 v = *(const f32x4*)(W + (size_t)(k0 + kr) * Dd + n0 + c4 * 4);
    *(f32x4*)&tile[kr][c4 * 4] = v * scale;
  }
  __syncthreads();
#pragma unroll
  for (int it = 0; it < 2; ++it) {
    int chunk = tid + it * 256;        // 512 chunks: 64 n-rows x 8 bf16x8
    int n = chunk & 63, k8 = chunk >> 6;
    bf16x8 o;
#pragma unroll
    for (int j = 0; j < 8; ++j) o[j] = (bf16)tile[k8 * 8 + j][n];
    *(bf16x8*)(Wt + (size_t)(n0 + n) * Dd + k0 + k8 * 8) = o;
  }
}

// ---------------------------------------------------------------- pack qkv bias
__global__ void pack_bias_kernel(const float* __restrict__ bq, const float* __restrict__ bk,
                                 const float* __restrict__ bv, float* __restrict__ outb) {
  int i = blockIdx.x * 256 + threadIdx.x;   // 0..3071
  float v = (i < 1024) ? bq[i] * CEXP : (i < 2048 ? bk[i - 1024] : bv[i - 2048]);
  outb[i] = v;
}

// ------------------------- GEMM: C[M][N] = A[M][K] @ Bt[N][K]^T + bias, bf16 MFMA
template <typename OutT>
__global__ __launch_bounds__(256)
void gemm_bf16_kernel(const bf16* __restrict__ A, const bf16* __restrict__ Bt,
                      const float* __restrict__ bias, OutT* __restrict__ C,
                      int M, int N, int K) {
  __shared__ alignas(16) bf16 As[128][72];
  __shared__ alignas(16) bf16 Bs[128][72];
  const int tid = threadIdx.x;
  const int lane = tid & 63, wave = tid >> 6;
  const int col = lane & 15, quad = lane >> 4;
  const int wr = (wave >> 1) * 64, wc = (wave & 1) * 64;
  const size_t m0 = (size_t)blockIdx.x * 128, n0 = (size_t)blockIdx.y * 128;

  f32x4 acc[4][4];
#pragma unroll
  for (int i = 0; i < 4; ++i)
#pragma unroll
    for (int j = 0; j < 4; ++j)
#pragma unroll
      for (int r = 0; r < 4; ++r) acc[i][j][r] = 0.f;

  for (int k0 = 0; k0 < K; k0 += 64) {
#pragma unroll
    for (int it = 0; it < 4; ++it) {
      int chunk = tid + it * 256;
      int rr = chunk >> 3, c8 = chunk & 7;
      *(bf16x8*)&As[rr][c8 * 8] = *(const bf16x8*)(A + (m0 + rr) * (size_t)K + k0 + c8 * 8);
      *(bf16x8*)&Bs[rr][c8 * 8] = *(const bf16x8*)(Bt + (n0 + rr) * (size_t)K + k0 + c8 * 8);
    }
    __syncthreads();
#pragma unroll
    for (int kk = 0; kk < 2; ++kk) {
      bf16x8 af[4], bfr[4];
#pragma unroll
      for (int i = 0; i < 4; ++i) af[i] = *(const bf16x8*)&As[wr + i * 16 + col][kk * 32 + quad * 8];
#pragma unroll
      for (int j = 0; j < 4; ++j) bfr[j] = *(const bf16x8*)&Bs[wc + j * 16 + col][kk * 32 + quad * 8];
#pragma unroll
      for (int i = 0; i < 4; ++i)
#pragma unroll
        for (int j = 0; j < 4; ++j) acc[i][j] = MFMA16(af[i], bfr[j], acc[i][j]);
    }
    __syncthreads();
  }
#pragma unroll
  for (int i = 0; i < 4; ++i)
#pragma unroll
    for (int j = 0; j < 4; ++j) {
      size_t row = m0 + wr + i * 16 + quad * 4;
      size_t c = n0 + wc + j * 16 + col;
      float bv = bias[c];
#pragma unroll
      for (int r = 0; r < 4; ++r) C[(row + r) * (size_t)N + c] = (OutT)(acc[i][j][r] + bv);
    }
}

// --------------------------- V transpose: QKV V-part [t][d] -> Vt[b][h][d][t] bf16
__global__ void transpose_v_kernel(const bf16* __restrict__ qkv, bf16* __restrict__ vt) {
  __shared__ alignas(16) bf16 tile[64][72];   // [d][t]
  const int tid = threadIdx.x;
  const int t0 = blockIdx.x * 64;
  const int h = blockIdx.y, b = blockIdx.z;
  const bf16* src = qkv + (size_t)(b * Tt + t0) * 3072 + 2048 + h * Hd;
#pragma unroll
  for (int it = 0; it < 2; ++it) {
    int chunk = tid + it * 256;
    int tr = chunk >> 3, d8 = chunk & 7;
    bf16x8 v = *(const bf16x8*)(src + (size_t)tr * 3072 + d8 * 8);
#pragma unroll
    for (int j = 0; j < 8; ++j) tile[d8 * 8 + j][tr] = v[j];
  }
  __syncthreads();
  bf16* dst = vt + ((size_t)(b * Hh + h) * Hd) * Tt + t0;
#pragma unroll
  for (int it = 0; it < 2; ++it) {
    int chunk = tid + it * 256;
    int d = chunk >> 3, t8 = chunk & 7;
    bf16x8 o = *(const bf16x8*)&tile[d][t8 * 8];
    *(bf16x8*)(dst + (size_t)d * Tt + t8 * 8) = o;
  }
}

// ----------------------------------------------- flash attention, transposed algebra
// MFMA16(X,Y,C): C[m][n] = sum_k X[m][k]*Y[n][k]; C layout col(lane&15)=n, row(quad*4+r)=m.
// S^T = MFMA(kf, qf): col=query, row=key -> lane holds 4 CONSECUTIVE keys ->
// packed b64 P writes to pbuf[query][key]; O^T = MFMA(vf, pf) reads pbuf rows b128.
// l = MFMA(ones, pf) -> col=query, matches O^T. Q pre-scaled by CEXP (folded in Wq/bq);
// fixed-reference softmax (scores ~N(0,1)); exact after final O/l.
// 1-D grid 1024, id%8 = XCD -> all q-tiles of one (b,h) pinned to one XCD L2.
__global__ __launch_bounds__(256, 4)
void flash_attn_kernel(const bf16* __restrict__ qkv, const bf16* __restrict__ vt,
                       const unsigned char* __restrict__ mask, bf16* __restrict__ ao) {
  __shared__ alignas(16) bf16 Ks[64][72];       // [key][d]
  __shared__ alignas(16) bf16 Vs[64][72];       // [d][key]
  __shared__ alignas(16) bf16 pbuf[4][2][16][72];  // [wave][t][query][key]

  const int tid = threadIdx.x;
  const int wave = tid >> 6, lane = tid & 63;
  const int col = lane & 15, quad = lane >> 4;
  const int id = blockIdx.x;
  const int hb = id & 63, qi = id >> 6;
  const int h = hb & 15, b = hb >> 4;
  const int qbase = qi * 128 + wave * 32;

  const bf16* Qp = qkv + (size_t)(b * Tt) * 3072 + h * Hd;
  const bf16* Kp = Qp + 1024;
  const bf16* Vp = vt + ((size_t)(b * Hh + h) * Hd) * Tt;
  const unsigned char* mp = mask + b * Tt;

  // mask any-nonzero flags for the 32 key-blocks, via ballot (no LDS):
  // lane l covers bytes [l*32, l*32+32); block i flag = ballot bits 2i,2i+1.
  unsigned long long anym;
  {
    const unsigned long long* mq = (const unsigned long long*)mp;
    unsigned long long acc = 0;
#pragma unroll
    for (int j = 0; j < 4; ++j) acc |= mq[lane * 4 + j];
    anym = __ballot(acc != 0ull);
  }

  // cooperative staging map: thread -> (row srow, 16-elem chunk scol)
  const int srow = tid >> 2, scol = (tid & 3) * 16;
  const bf16* Ksrc = Kp + (size_t)srow * 3072 + scol;   // + kb*3072
  const bf16* Vsrc = Vp + (size_t)srow * Tt + scol;     // + kb

  // Q fragments (pre-scaled by CEXP): free index = query = lane&15
  bf16x8 qf[2][2];
#pragma unroll
  for (int t = 0; t < 2; ++t)
#pragma unroll
    for (int kk = 0; kk < 2; ++kk)
      qf[t][kk] = *(const bf16x8*)(Qp + (size_t)(qbase + t * 16 + col) * 3072 + kk * 32 + quad * 8);

  // stage tile 0
  {
    bf16x8 k0 = *(const bf16x8*)Ksrc, k1 = *(const bf16x8*)(Ksrc + 8);
    bf16x8 v0 = *(const bf16x8*)Vsrc, v1 = *(const bf16x8*)(Vsrc + 8);
    *(bf16x8*)&Ks[srow][scol] = k0;  *(bf16x8*)&Ks[srow][scol + 8] = k1;
    *(bf16x8*)&Vs[srow][scol] = v0;  *(bf16x8*)&Vs[srow][scol + 8] = v1;
  }
  __syncthreads();

  f32x4 oacc[2][4], lacc[2];
#pragma unroll
  for (int t = 0; t < 2; ++t) {
#pragma unroll
    for (int r = 0; r < 4; ++r) lacc[t][r] = 0.f;
#pragma unroll
    for (int n = 0; n < 4; ++n)
#pragma unroll
      for (int r = 0; r < 4; ++r) oacc[t][n][r] = 0.f;
  }
  bf16x8 ones;
#pragma unroll
  for (int j = 0; j < 8; ++j) ones[j] = (bf16)1.0f;

  for (int i = 0; i < 32; ++i) {
    const int kb = i * 64;

    // prefetch next K/V tile into registers (consumed after barrier below)
    bf16x8 nk0, nk1, nv0, nv1;
    if (i < 31) {
      const bf16* ks = Ksrc + (size_t)(kb + 64) * 3072;
      const bf16* vs = Vsrc + (kb + 64);
      nk0 = *(const bf16x8*)ks;  nk1 = *(const bf16x8*)(ks + 8);
      nv0 = *(const bf16x8*)vs;  nv1 = *(const bf16x8*)(vs + 8);
    }

    // fragments: kf free=key, vf free=d
    bf16x8 kf[4][2], vf[4][2];
#pragma unroll
    for (int kt = 0; kt < 4; ++kt)
#pragma unroll
      for (int kk = 0; kk < 2; ++kk)
        kf[kt][kk] = *(const bf16x8*)&Ks[kt * 16 + col][kk * 32 + quad * 8];
#pragma unroll
    for (int n = 0; n < 4; ++n)
#pragma unroll
      for (int kk = 0; kk < 2; ++kk)
        vf[n][kk] = *(const bf16x8*)&Vs[n * 16 + col][kk * 32 + quad * 8];

    // S^T: col=query(t*16+col... per-lane col), row=key = kt*16+quad*4+r
    f32x4 s[2][4];
#pragma unroll
    for (int t = 0; t < 2; ++t)
#pragma unroll
      for (int kt = 0; kt < 4; ++kt)
#pragma unroll
        for (int r = 0; r < 4; ++r) s[t][kt][r] = 0.f;
#pragma unroll
    for (int kk = 0; kk < 2; ++kk)
#pragma unroll
      for (int t = 0; t < 2; ++t)
#pragma unroll
        for (int kt = 0; kt < 4; ++kt) s[t][kt] = MFMA16(kf[kt][kk], qf[t][kk], s[t][kt]);

    if ((anym >> (2 * i)) & 3ull) {   // uniform slow path: some key in this block masked
#pragma unroll
      for (int kt = 0; kt < 4; ++kt)
#pragma unroll
        for (int r = 0; r < 4; ++r) {
          bool mk = mp[kb + kt * 16 + quad * 4 + r] != 0;
          if (mk) { s[0][kt][r] = -1e9f; s[1][kt][r] = -1e9f; }
        }
    }

    // P = exp2(S); packed b64 write; O^T += V^T.P, l += 1.P
#pragma unroll
    for (int t = 0; t < 2; ++t) {
#pragma unroll
      for (int kt = 0; kt < 4; ++kt) {
        bf16x4 pk;
#pragma unroll
        for (int r = 0; r < 4; ++r) pk[r] = (bf16)__builtin_amdgcn_exp2f(s[t][kt][r]);
        *(bf16x4*)&pbuf[wave][t][col][kt * 16 + quad * 4] = pk;
      }
    }
    __builtin_amdgcn_s_waitcnt(0xc07f);  // lgkmcnt(0): P visible to this wave's reads
#pragma unroll
    for (int t = 0; t < 2; ++t) {
      bf16x8 pf[2];
#pragma unroll
      for (int kk = 0; kk < 2; ++kk)
        pf[kk] = *(const bf16x8*)&pbuf[wave][t][col][kk * 32 + quad * 8];
#pragma unroll
      for (int kk = 0; kk < 2; ++kk) {
#pragma unroll
        for (int n = 0; n < 4; ++n) oacc[t][n] = MFMA16(vf[n][kk], pf[kk], oacc[t][n]);
        lacc[t] = MFMA16(ones, pf[kk], lacc[t]);
      }
    }

    __syncthreads();                 // all waves done reading Ks/Vs
    if (i < 31) {
      *(bf16x8*)&Ks[srow][scol] = nk0;  *(bf16x8*)&Ks[srow][scol + 8] = nk1;
      *(bf16x8*)&Vs[srow][scol] = nv0;  *(bf16x8*)&Vs[srow][scol + 8] = nv1;
    }
    __syncthreads();                 // next tile visible
  }

  // epilogue: O^T layout col=query, row=d=quad*4+r -> packed bf16x4 stores
  float rl[2] = {1.0f / lacc[0][0], 1.0f / lacc[1][0]};
#pragma unroll
  for (int t = 0; t < 2; ++t) {
    size_t q = (size_t)b * Tt + qbase + t * 16 + col;
#pragma unroll
    for (int n = 0; n < 4; ++n) {
      bf16x4 ov;
#pragma unroll
      for (int r = 0; r < 4; ++r) ov[r] = (bf16)(oacc[t][n][r] * rl[t]);
      *(bf16x4*)(ao + q * Dd + h * Hd + n * 16 + quad * 4) = ov;
    }
  }
}

// --------------------------------------------------------------------- launcher
extern "C" void kernel_launch(void* const* d_in, const int* in_sizes, int n_in,
                              void* d_out, int out_size, void* d_ws, size_t ws_size,
                              hipStream_t stream) {
  const float* x = (const float*)d_in[0];
  const unsigned char* mask = (const unsigned char*)d_in[1];
  const float* Wq = (const float*)d_in[2];
  const float* bq = (const float*)d_in[3];
  const float* Wk = (const float*)d_in[4];
  const float* bk = (const float*)d_in[5];
  const float* Wv = (const float*)d_in[6];
  const float* bv = (const float*)d_in[7];
  const float* Wo = (const float*)d_in[8];
  const float* bo = (const float*)d_in[9];
  float* out = (float*)d_out;

  char* ws = (char*)d_ws;
  size_t off = 0;
  auto alloc = [&](size_t bytes) {
    char* p = ws + off;
    off += (bytes + 255) & ~(size_t)255;
    return p;
  };
  bf16* xb  = (bf16*)alloc((size_t)Mrows * Dd * 2);        // 16.8MB (reused as AO)
  bf16* Wt  = (bf16*)alloc((size_t)3 * Dd * Dd * 2);       // 6.3MB  packed [3072][1024]
  bf16* Wot = (bf16*)alloc((size_t)Dd * Dd * 2);           // 2.1MB
  bf16* QKV = (bf16*)alloc((size_t)Mrows * 3 * Dd * 2);    // 50.3MB [8192][3072]
  bf16* Vt  = (bf16*)alloc((size_t)Bb * Hh * Hd * Tt * 2); // 16.8MB
  float* bqkv = (float*)alloc((size_t)3 * Dd * 4);

  cast_f32_bf16_kernel<<<Mrows * Dd / (256 * 8), 256, 0, stream>>>(x, xb);
  transpose_cast_w_kernel<<<dim3(16, 16), 256, 0, stream>>>(Wq, Wt, CEXP);  // fold softmax scale
  transpose_cast_w_kernel<<<dim3(16, 16), 256, 0, stream>>>(Wk, Wt + (size_t)Dd * Dd, 1.0f);
  transpose_cast_w_kernel<<<dim3(16, 16), 256, 0, stream>>>(Wv, Wt + (size_t)2 * Dd * Dd, 1.0f);
  transpose_cast_w_kernel<<<dim3(16, 16), 256, 0, stream>>>(Wo, Wot, 1.0f);
  pack_bias_kernel<<<12, 256, 0, stream>>>(bq, bk, bv, bqkv);

  gemm_bf16_kernel<bf16><<<dim3(Mrows / 128, 3 * Dd / 128), 256, 0, stream>>>(
      xb, Wt, bqkv, QKV, Mrows, 3 * Dd, Dd);
  transpose_v_kernel<<<dim3(Tt / 64, Hh, Bb), 256, 0, stream>>>(QKV, Vt);

  bf16* AO = xb;  // xb dead after QKV GEMM
  flash_attn_kernel<<<dim3(1024), 256, 0, stream>>>(QKV, Vt, mask, AO);
  gemm_bf16_kernel<float><<<dim3(Mrows / 128, Dd / 128), 256, 0, stream>>>(
      AO, Wot, bo, out, Mrows, Dd, Dd);
}

// Round 5
// 297.450 us; speedup vs baseline: 1.1697x; 1.1697x over previous
//
#include <hip/hip_runtime.h>

using bf16 = __bf16;
typedef bf16 bf16x4 __attribute__((ext_vector_type(4)));
typedef bf16 bf16x8 __attribute__((ext_vector_type(8)));
typedef float f32x4 __attribute__((ext_vector_type(4)));
typedef float f32x8 __attribute__((ext_vector_type(8)));

#define MFMA16(a, b, c) __builtin_amdgcn_mfma_f32_16x16x32_bf16(a, b, c, 0, 0, 0)

constexpr int Bb = 4, Tt = 2048, Dd = 1024, Hh = 16, Hd = 64;
constexpr int Mrows = Bb * Tt;                 // 8192
constexpr float CEXP = 0.18033688011112042f;   // (1/sqrt(64)) * log2(e), folded into Wq/bq

// ---------------------------------------------------------------- cast x -> bf16
__global__ void cast_f32_bf16_kernel(const float* __restrict__ in, bf16* __restrict__ out) {
  size_t i = ((size_t)blockIdx.x * 256 + threadIdx.x) * 8;
  f32x8 v = *(const f32x8*)(in + i);
  *(bf16x8*)(out + i) = __builtin_convertvector(v, bf16x8);
}

// ------------------- transpose+cast W[k][n] f32 -> Wt[n][k] bf16, optional scale
__global__ void transpose_cast_w_kernel(const float* __restrict__ W, bf16* __restrict__ Wt,
                                        float scale) {
  __shared__ alignas(16) float tile[64][68];
  const int tid = threadIdx.x;
  const int n0 = blockIdx.x * 64, k0 = blockIdx.y * 64;
#pragma unroll
  for (int it = 0; it < 4; ++it) {
    int chunk = tid + it * 256;        // 1024 chunks: 64 k-rows x 16 float4
    int kr = chunk >> 4, c4 = chunk & 15;
    f32x4 v = *(const f32x4*)(W + (size_t)(k0 + kr) * Dd + n0 + c4 * 4);
    *(f32x4*)&tile[kr][c4 * 4] = v * scale;
  }
  __syncthreads();
#pragma unroll
  for (int it = 0; it < 2; ++it) {
    int chunk = tid + it * 256;        // 512 chunks: 64 n-rows x 8 bf16x8
    int n = chunk & 63, k8 = chunk >> 6;
    bf16x8 o;
#pragma unroll
    for (int j = 0; j < 8; ++j) o[j] = (bf16)tile[k8 * 8 + j][n];
    *(bf16x8*)(Wt + (size_t)(n0 + n) * Dd + k0 + k8 * 8) = o;
  }
}

// ---------------------------------------------------------------- pack qkv bias
__global__ void pack_bias_kernel(const float* __restrict__ bq, const float* __restrict__ bk,
                                 const float* __restrict__ bv, float* __restrict__ outb) {
  int i = blockIdx.x * 256 + threadIdx.x;   // 0..3071
  float v = (i < 1024) ? bq[i] * CEXP : (i < 2048 ? bk[i - 1024] : bv[i - 2048]);
  outb[i] = v;
}

// ------------------------- GEMM: C[M][N] = A[M][K] @ Bt[N][K]^T + bias, bf16 MFMA
template <typename OutT>
__global__ __launch_bounds__(256)
void gemm_bf16_kernel(const bf16* __restrict__ A, const bf16* __restrict__ Bt,
                      const float* __restrict__ bias, OutT* __restrict__ C,
                      int M, int N, int K) {
  __shared__ alignas(16) bf16 As[128][72];
  __shared__ alignas(16) bf16 Bs[128][72];
  const int tid = threadIdx.x;
  const int lane = tid & 63, wave = tid >> 6;
  const int col = lane & 15, quad = lane >> 4;
  const int wr = (wave >> 1) * 64, wc = (wave & 1) * 64;
  const size_t m0 = (size_t)blockIdx.x * 128, n0 = (size_t)blockIdx.y * 128;

  f32x4 acc[4][4];
#pragma unroll
  for (int i = 0; i < 4; ++i)
#pragma unroll
    for (int j = 0; j < 4; ++j)
#pragma unroll
      for (int r = 0; r < 4; ++r) acc[i][j][r] = 0.f;

  for (int k0 = 0; k0 < K; k0 += 64) {
#pragma unroll
    for (int it = 0; it < 4; ++it) {
      int chunk = tid + it * 256;
      int rr = chunk >> 3, c8 = chunk & 7;
      *(bf16x8*)&As[rr][c8 * 8] = *(const bf16x8*)(A + (m0 + rr) * (size_t)K + k0 + c8 * 8);
      *(bf16x8*)&Bs[rr][c8 * 8] = *(const bf16x8*)(Bt + (n0 + rr) * (size_t)K + k0 + c8 * 8);
    }
    __syncthreads();
#pragma unroll
    for (int kk = 0; kk < 2; ++kk) {
      bf16x8 af[4], bfr[4];
#pragma unroll
      for (int i = 0; i < 4; ++i) af[i] = *(const bf16x8*)&As[wr + i * 16 + col][kk * 32 + quad * 8];
#pragma unroll
      for (int j = 0; j < 4; ++j) bfr[j] = *(const bf16x8*)&Bs[wc + j * 16 + col][kk * 32 + quad * 8];
#pragma unroll
      for (int i = 0; i < 4; ++i)
#pragma unroll
        for (int j = 0; j < 4; ++j) acc[i][j] = MFMA16(af[i], bfr[j], acc[i][j]);
    }
    __syncthreads();
  }
#pragma unroll
  for (int i = 0; i < 4; ++i)
#pragma unroll
    for (int j = 0; j < 4; ++j) {
      size_t row = m0 + wr + i * 16 + quad * 4;
      size_t c = n0 + wc + j * 16 + col;
      float bv = bias[c];
#pragma unroll
      for (int r = 0; r < 4; ++r) C[(row + r) * (size_t)N + c] = (OutT)(acc[i][j][r] + bv);
    }
}

// --------------------------- V transpose: QKV V-part [t][d] -> Vt[b][h][d][t] bf16
__global__ void transpose_v_kernel(const bf16* __restrict__ qkv, bf16* __restrict__ vt) {
  __shared__ alignas(16) bf16 tile[64][72];   // [d][t]
  const int tid = threadIdx.x;
  const int t0 = blockIdx.x * 64;
  const int h = blockIdx.y, b = blockIdx.z;
  const bf16* src = qkv + (size_t)(b * Tt + t0) * 3072 + 2048 + h * Hd;
#pragma unroll
  for (int it = 0; it < 2; ++it) {
    int chunk = tid + it * 256;
    int tr = chunk >> 3, d8 = chunk & 7;
    bf16x8 v = *(const bf16x8*)(src + (size_t)tr * 3072 + d8 * 8);
#pragma unroll
    for (int j = 0; j < 8; ++j) tile[d8 * 8 + j][tr] = v[j];
  }
  __syncthreads();
  bf16* dst = vt + ((size_t)(b * Hh + h) * Hd) * Tt + t0;
#pragma unroll
  for (int it = 0; it < 2; ++it) {
    int chunk = tid + it * 256;
    int d = chunk >> 3, t8 = chunk & 7;
    bf16x8 o = *(const bf16x8*)&tile[d][t8 * 8];
    *(bf16x8*)(dst + (size_t)d * Tt + t8 * 8) = o;
  }
}

// ----------------------------------------------- flash attention, 256 Q-rows/block
// Grid 512 = 2 blocks/CU exactly (no dispatch tail). 4 waves x 64 Q-rows (t=0..3).
// Transposed algebra: S^T = MFMA(kf,qf) -> lane holds 4 consecutive keys (packed b64
// P writes); O^T = MFMA(vf,pf). Row-sum l on VALU (lane owns one query column).
// K/V tiles (64 keys) double-buffered in XOR-swizzled LDS (16B slot s = chunk^(row&7),
// no padding -> bank-minimal frag reads); register prefetch + ONE barrier per iter.
// __launch_bounds__(256,2): 256-reg budget, live set ~224 -> no spill (R4's
// (256,4) bound forced spills: 243MB scratch writes).
__global__ __launch_bounds__(256, 2)
void flash_attn_kernel(const bf16* __restrict__ qkv, const bf16* __restrict__ vt,
                       const unsigned char* __restrict__ mask, bf16* __restrict__ ao) {
  __shared__ alignas(16) bf16 Ks[2][64 * 64];     // [key][slot^], 8KB each
  __shared__ alignas(16) bf16 Vs[2][64 * 64];     // [d][slot^]
  __shared__ alignas(16) bf16 pbuf[4][16 * 64];   // per-wave [query][slot^]

  const int tid = threadIdx.x;
  const int wave = tid >> 6, lane = tid & 63;
  const int col = lane & 15, quad = lane >> 4;
  const int id = blockIdx.x;
  const int hb = id & 63, qi2 = id >> 6;          // id%8 = hb%8 -> XCD pinning
  const int h = hb & 15, b = hb >> 4;
  const int qbase0 = qi2 * 256 + wave * 64;

  const bf16* Qp = qkv + (size_t)(b * Tt) * 3072 + h * Hd;
  const bf16* Kp = Qp + 1024;
  const bf16* Vp = vt + ((size_t)(b * Hh + h) * Hd) * Tt;
  const unsigned char* mp = mask + b * Tt;

  // mask any-nonzero flags for the 32 key-blocks via ballot
  unsigned long long anym;
  {
    const unsigned long long* mq = (const unsigned long long*)mp;
    unsigned long long acc = 0;
#pragma unroll
    for (int j = 0; j < 4; ++j) acc |= mq[lane * 4 + j];
    anym = __ballot(acc != 0ull);
  }

  // Q fragments (pre-scaled by CEXP): free index = query
  bf16x8 qf[4][2];
#pragma unroll
  for (int t = 0; t < 4; ++t)
#pragma unroll
    for (int kk = 0; kk < 2; ++kk)
      qf[t][kk] = *(const bf16x8*)(Qp + (size_t)(qbase0 + t * 16 + col) * 3072 + kk * 32 + quad * 8);

  // staging map: row = lane, wave w stages 16B chunks {2w, 2w+1} of each row
  const bf16* Ksrc = Kp + (size_t)lane * 3072 + wave * 16;   // + kb*3072
  const bf16* Vsrc = Vp + (size_t)lane * Tt + wave * 16;     // + kb
  const int ss1 = ((2 * wave) ^ (lane & 7)) * 8;             // xor'd slot offsets (elems)
  const int ss2 = ((2 * wave + 1) ^ (lane & 7)) * 8;
  const int srowoff = lane * 64;

  // stage tile 0
  {
    bf16x8 k0 = *(const bf16x8*)Ksrc, k1 = *(const bf16x8*)(Ksrc + 8);
    bf16x8 v0 = *(const bf16x8*)Vsrc, v1 = *(const bf16x8*)(Vsrc + 8);
    *(bf16x8*)&Ks[0][srowoff + ss1] = k0;  *(bf16x8*)&Ks[0][srowoff + ss2] = k1;
    *(bf16x8*)&Vs[0][srowoff + ss1] = v0;  *(bf16x8*)&Vs[0][srowoff + ss2] = v1;
  }
  __syncthreads();

  f32x4 oacc[4][4];
  float lsum[4];
#pragma unroll
  for (int t = 0; t < 4; ++t) {
    lsum[t] = 0.f;
#pragma unroll
    for (int n = 0; n < 4; ++n)
#pragma unroll
      for (int r = 0; r < 4; ++r) oacc[t][n][r] = 0.f;
  }

  const int fslot0 = ((0 * 4 + quad) ^ (col & 7)) * 8;   // kk=0 xor'd frag slot (elems)
  const int fslot1 = ((1 * 4 + quad) ^ (col & 7)) * 8;   // kk=1

  for (int i = 0; i < 32; ++i) {
    const int cur = i & 1, nxt = cur ^ 1;
    const int kb = i * 64;

    // prefetch next K/V tile into registers (written to LDS after compute)
    bf16x8 nk0, nk1, nv0, nv1;
    if (i < 31) {
      const bf16* ks = Ksrc + (size_t)(kb + 64) * 3072;
      const bf16* vs = Vsrc + (kb + 64);
      nk0 = *(const bf16x8*)ks;  nk1 = *(const bf16x8*)(ks + 8);
      nv0 = *(const bf16x8*)vs;  nv1 = *(const bf16x8*)(vs + 8);
    }

    // fragments from swizzled LDS: kf free=key, vf free=d
    bf16x8 kf[4][2], vf[4][2];
#pragma unroll
    for (int kt = 0; kt < 4; ++kt) {
      kf[kt][0] = *(const bf16x8*)&Ks[cur][(kt * 16 + col) * 64 + fslot0];
      kf[kt][1] = *(const bf16x8*)&Ks[cur][(kt * 16 + col) * 64 + fslot1];
    }
#pragma unroll
    for (int n = 0; n < 4; ++n) {
      vf[n][0] = *(const bf16x8*)&Vs[cur][(n * 16 + col) * 64 + fslot0];
      vf[n][1] = *(const bf16x8*)&Vs[cur][(n * 16 + col) * 64 + fslot1];
    }

#pragma unroll
    for (int t = 0; t < 4; ++t) {
      // S^T tile: col=query, row=key(kt*16+quad*4+r)
      f32x4 s[4];
#pragma unroll
      for (int kt = 0; kt < 4; ++kt)
#pragma unroll
        for (int r = 0; r < 4; ++r) s[kt][r] = 0.f;
#pragma unroll
      for (int kk = 0; kk < 2; ++kk)
#pragma unroll
        for (int kt = 0; kt < 4; ++kt) s[kt] = MFMA16(kf[kt][kk], qf[t][kk], s[kt]);

      if ((anym >> (2 * i)) & 3ull) {   // uniform slow path
#pragma unroll
        for (int kt = 0; kt < 4; ++kt)
#pragma unroll
          for (int r = 0; r < 4; ++r)
            if (mp[kb + kt * 16 + quad * 4 + r] != 0) s[kt][r] = -1e9f;
      }

      // P = exp2(S); packed b64 writes to xor'd pbuf; VALU row-sum
      float rs = 0.f;
#pragma unroll
      for (int kt = 0; kt < 4; ++kt) {
        bf16x4 pk;
#pragma unroll
        for (int r = 0; r < 4; ++r) {
          float p = __builtin_amdgcn_exp2f(s[kt][r]);
          rs += p;
          pk[r] = (bf16)p;
        }
        int slot = ((2 * kt + (quad >> 1)) ^ (col & 7)) * 8 + (quad & 1) * 4;
        *(bf16x4*)&pbuf[wave][col * 64 + slot] = pk;
      }
      __builtin_amdgcn_s_waitcnt(0xc07f);  // lgkmcnt(0): P visible to this wave
      bf16x8 pf0 = *(const bf16x8*)&pbuf[wave][col * 64 + fslot0];
      bf16x8 pf1 = *(const bf16x8*)&pbuf[wave][col * 64 + fslot1];
#pragma unroll
      for (int n = 0; n < 4; ++n) {
        oacc[t][n] = MFMA16(vf[n][0], pf0, oacc[t][n]);
        oacc[t][n] = MFMA16(vf[n][1], pf1, oacc[t][n]);
      }
      rs += __shfl_xor(rs, 16, 64);
      rs += __shfl_xor(rs, 32, 64);
      lsum[t] += rs;
    }

    // write prefetched tile to nxt, then the single per-iter barrier
    if (i < 31) {
      *(bf16x8*)&Ks[nxt][srowoff + ss1] = nk0;  *(bf16x8*)&Ks[nxt][srowoff + ss2] = nk1;
      *(bf16x8*)&Vs[nxt][srowoff + ss1] = nv0;  *(bf16x8*)&Vs[nxt][srowoff + ss2] = nv1;
    }
    __syncthreads();
  }

  // epilogue: O^T col=query, row=d=n*16+quad*4+r -> packed bf16x4 stores
#pragma unroll
  for (int t = 0; t < 4; ++t) {
    float rl = 1.0f / lsum[t];
    size_t q = (size_t)b * Tt + qbase0 + t * 16 + col;
#pragma unroll
    for (int n = 0; n < 4; ++n) {
      bf16x4 ov;
#pragma unroll
      for (int r = 0; r < 4; ++r) ov[r] = (bf16)(oacc[t][n][r] * rl);
      *(bf16x4*)(ao + q * Dd + h * Hd + n * 16 + quad * 4) = ov;
    }
  }
}

// --------------------------------------------------------------------- launcher
extern "C" void kernel_launch(void* const* d_in, const int* in_sizes, int n_in,
                              void* d_out, int out_size, void* d_ws, size_t ws_size,
                              hipStream_t stream) {
  const float* x = (const float*)d_in[0];
  const unsigned char* mask = (const unsigned char*)d_in[1];
  const float* Wq = (const float*)d_in[2];
  const float* bq = (const float*)d_in[3];
  const float* Wk = (const float*)d_in[4];
  const float* bk = (const float*)d_in[5];
  const float* Wv = (const float*)d_in[6];
  const float* bv = (const float*)d_in[7];
  const float* Wo = (const float*)d_in[8];
  const float* bo = (const float*)d_in[9];
  float* out = (float*)d_out;

  char* ws = (char*)d_ws;
  size_t off = 0;
  auto alloc = [&](size_t bytes) {
    char* p = ws + off;
    off += (bytes + 255) & ~(size_t)255;
    return p;
  };
  bf16* xb  = (bf16*)alloc((size_t)Mrows * Dd * 2);        // 16.8MB (reused as AO)
  bf16* Wt  = (bf16*)alloc((size_t)3 * Dd * Dd * 2);       // 6.3MB  packed [3072][1024]
  bf16* Wot = (bf16*)alloc((size_t)Dd * Dd * 2);           // 2.1MB
  bf16* QKV = (bf16*)alloc((size_t)Mrows * 3 * Dd * 2);    // 50.3MB [8192][3072]
  bf16* Vt  = (bf16*)alloc((size_t)Bb * Hh * Hd * Tt * 2); // 16.8MB
  float* bqkv = (float*)alloc((size_t)3 * Dd * 4);

  cast_f32_bf16_kernel<<<Mrows * Dd / (256 * 8), 256, 0, stream>>>(x, xb);
  transpose_cast_w_kernel<<<dim3(16, 16), 256, 0, stream>>>(Wq, Wt, CEXP);  // fold softmax scale
  transpose_cast_w_kernel<<<dim3(16, 16), 256, 0, stream>>>(Wk, Wt + (size_t)Dd * Dd, 1.0f);
  transpose_cast_w_kernel<<<dim3(16, 16), 256, 0, stream>>>(Wv, Wt + (size_t)2 * Dd * Dd, 1.0f);
  transpose_cast_w_kernel<<<dim3(16, 16), 256, 0, stream>>>(Wo, Wot, 1.0f);
  pack_bias_kernel<<<12, 256, 0, stream>>>(bq, bk, bv, bqkv);

  gemm_bf16_kernel<bf16><<<dim3(Mrows / 128, 3 * Dd / 128), 256, 0, stream>>>(
      xb, Wt, bqkv, QKV, Mrows, 3 * Dd, Dd);
  transpose_v_kernel<<<dim3(Tt / 64, Hh, Bb), 256, 0, stream>>>(QKV, Vt);

  bf16* AO = xb;  // xb dead after QKV GEMM
  flash_attn_kernel<<<dim3(512), 256, 0, stream>>>(QKV, Vt, mask, AO);
  gemm_bf16_kernel<float><<<dim3(Mrows / 128, Dd / 128), 256, 0, stream>>>(
      AO, Wot, bo, out, Mrows, Dd, Dd);
}